// Round 4
// baseline (451.766 us; speedup 1.0000x reference)
//
#include <hip/hip_runtime.h>

// LIF neuron forward scan, x: [B=64, F=2048, T=512] f32 (scan over contiguous T).
//   v = v + (x_t - v) * (DT/TAU);  s = (v >= 1); v *= (1 - s)
//
// Structure: one wave (64 threads) per block, 64 rows/block, T chunked by 64.
// - Global->reg 2-deep prefetch (bufA/bufB), coalesced nontemporal float4.
// - Reg->LDS transpose with per-element XOR swizzle tile[c][r^c]; conflict-free
//   in both staging and the lane-per-row scan (validated rounds 1-2).
// - Output is statistically all zeros (threshold = 6.2 sigma of the membrane
//   EMA): stores are decoupled as fire-and-forget zero-stores; rare spikes are
//   scattered behind a vmcnt(0) drain in an almost-never-taken branch (drain
//   orders the scatter after this chunk's own zero-stores -> race-free; each
//   row is written only by its owning block, so no cross-wave races).
// - No barriers (single-wave blocks); phases fenced with s_waitcnt lgkmcnt(0).
// - Chunk loop fully unrolled so every buf/address index is static (no scratch).

typedef float f4 __attribute__((ext_vector_type(4)));

#define T_LEN 512
#define CHUNK 64
#define NCHUNK (T_LEN / CHUNK)

__global__ __launch_bounds__(64, 2)
void lif_kernel(const float* __restrict__ x, float* __restrict__ out) {
    __shared__ float tile[CHUNK][64];   // 16 KB, XOR-swizzled columns
    const int lane = threadIdx.x;                 // 0..63
    const size_t row0 = (size_t)blockIdx.x * 64;  // 64 rows per block
    const float kk = 1.0f / 20.0f;                // DT / TAU
    float v = 0.0f;                               // membrane potential

    const float* xb = x + row0 * T_LEN;
    float* ob = out + row0 * T_LEN;

    // Staging geometry: lanes 0..15 cover one row's 64-float chunk contiguously.
    const int rL = lane >> 4;          // row sub-index 0..3
    const int cL = (lane & 15) * 4;    // t offset within chunk

    f4 bufA[16], bufB[16];             // 2-deep register prefetch (128 VGPRs)
    const f4 zero4 = {0.f, 0.f, 0.f, 0.f};

    // prologue: chunk 0 -> bufA, chunk 1 -> bufB
    #pragma unroll
    for (int p = 0; p < 16; ++p) {
        const int r = p * 4 + rL;
        bufA[p] = __builtin_nontemporal_load(
            (const f4*)(xb + (size_t)r * T_LEN + cL));
    }
    #pragma unroll
    for (int p = 0; p < 16; ++p) {
        const int r = p * 4 + rL;
        bufB[p] = __builtin_nontemporal_load(
            (const f4*)(xb + (size_t)r * T_LEN + CHUNK + cL));
    }

#define STEP(CH, BUF)                                                         \
    {                                                                         \
        /* prior compute's ds_reads done -> tile reusable */                  \
        asm volatile("s_waitcnt lgkmcnt(0)" ::: "memory");                    \
        _Pragma("unroll")                                                     \
        for (int p = 0; p < 16; ++p) {  /* regs -> LDS (swizzled) */          \
            const int r = p * 4 + rL;                                         \
            tile[cL + 0][r ^ (cL + 0)] = BUF[p][0];                           \
            tile[cL + 1][r ^ (cL + 1)] = BUF[p][1];                           \
            tile[cL + 2][r ^ (cL + 2)] = BUF[p][2];                           \
            tile[cL + 3][r ^ (cL + 3)] = BUF[p][3];                           \
        }                                                                     \
        if ((CH) + 2 < NCHUNK) {        /* prefetch chunk CH+2 */             \
            const float* xc = xb + (size_t)((CH) + 2) * CHUNK;                \
            _Pragma("unroll")                                                 \
            for (int p = 0; p < 16; ++p) {                                    \
                const int r = p * 4 + rL;                                     \
                BUF[p] = __builtin_nontemporal_load(                          \
                    (const f4*)(xc + (size_t)r * T_LEN + cL));                \
            }                                                                 \
        }                                                                     \
        {                               /* fire-and-forget zero output */     \
            float* oc = ob + (size_t)(CH) * CHUNK;                            \
            _Pragma("unroll")                                                 \
            for (int p = 0; p < 16; ++p) {                                    \
                const int r = p * 4 + rL;                                     \
                __builtin_nontemporal_store(                                  \
                    zero4, (f4*)(oc + (size_t)r * T_LEN + cL));               \
            }                                                                 \
        }                                                                     \
        asm volatile("s_waitcnt lgkmcnt(0)" ::: "memory");                    \
        unsigned long long spk = 0ull;                                        \
        _Pragma("unroll")                                                     \
        for (int t = 0; t < CHUNK; ++t) {  /* lane owns row row0+lane */      \
            const float xv = tile[t][lane ^ t];                               \
            v = v + (xv - v) * kk;                                            \
            const bool fire = (v >= 1.0f);                                    \
            spk |= ((unsigned long long)fire) << t;                           \
            v = fire ? 0.0f : v;                                              \
        }                                                                     \
        if (spk) {  /* ~never taken: 6.2-sigma events */                      \
            asm volatile("s_waitcnt vmcnt(0)" ::: "memory");                  \
            float* orow = out + (row0 + lane) * T_LEN + (size_t)(CH) * CHUNK; \
            while (spk) {                                                     \
                const int t = __builtin_ctzll(spk);                           \
                spk &= spk - 1;                                               \
                orow[t] = 1.0f;                                               \
            }                                                                 \
        }                                                                     \
    }

    STEP(0, bufA)
    STEP(1, bufB)
    STEP(2, bufA)
    STEP(3, bufB)
    STEP(4, bufA)
    STEP(5, bufB)
    STEP(6, bufA)
    STEP(7, bufB)
#undef STEP
}

extern "C" void kernel_launch(void* const* d_in, const int* in_sizes, int n_in,
                              void* d_out, int out_size, void* d_ws, size_t ws_size,
                              hipStream_t stream) {
    const float* x = (const float*)d_in[0];
    float* out = (float*)d_out;
    const int rows = in_sizes[0] / T_LEN;   // B*F = 131072
    const int grid = rows / 64;             // 2048 single-wave blocks
    lif_kernel<<<dim3(grid), dim3(64), 0, stream>>>(x, out);
}

// Round 5
// 430.043 us; speedup vs baseline: 1.0505x; 1.0505x over previous
//
#include <hip/hip_runtime.h>

// LIF neuron forward scan, x: [B=64, F=2048, T=512] f32 (scan over contiguous T).
//   v = v + (x_t - v) * (DT/TAU);  s = (v >= 1); v *= (1 - s)
//
// Wave-parallel affine-scan formulation (lanes = time):
//   - One wave processes one row (T=512) at a time: lane l holds t=8l..8l+7
//     as a float8 -> every wave load/store is 2KB fully sequential. No LDS.
//   - Linear LIF (no spike) is affine with CONSTANT alpha=(1-k): per-lane
//     8-step fold from v=0 gives beta_lane; a 6-step shfl_up Hillis-Steele
//     scan with compile-time multipliers alpha^(8*2^s) composes prefixes;
//     exclusive prefix = membrane entering the lane. Lane then re-runs the
//     EXACT serial recurrence on its 8 elements tracking max(v).
//   - If ballot(max >= 0.95) == 0 (margin 0.05 >> ~1e-6 compose rounding):
//     no spike anywhere in the row -> linear model exact -> store zeros.
//     This is the ~always case (threshold is 6.2 sigma; absmax=0 observed).
//   - Else (~never): exact serial re-scan of the whole row with resets,
//     bit-identical to the reference recurrence, decides the output.
//   - Rows independent (v0=0 per row) -> no cross-iteration carry; explicit
//     next-row prefetch keeps loads in flight.

typedef float f8 __attribute__((ext_vector_type(8)));

#define T_LEN 512
#define ROWS_PER_WAVE 16
#define WAVES_PER_BLOCK 4

__global__ __launch_bounds__(256, 8)
void lif_kernel(const float* __restrict__ x, float* __restrict__ out) {
    constexpr float  K  = 1.0f / 20.0f;
    constexpr double Kd = (double)(1.0f / 20.0f);
    constexpr double A1 = 1.0 - Kd;          // effective per-step decay
    constexpr double A2 = A1 * A1;
    constexpr double A4 = A2 * A2;
    constexpr double A8 = A4 * A4;           // per-lane segment (8 steps)
    constexpr double A16 = A8 * A8;
    constexpr double A32 = A16 * A16;
    constexpr double A64 = A32 * A32;
    constexpr double A128 = A64 * A64;
    constexpr double A256 = A128 * A128;
    constexpr float C[6] = {(float)A8,  (float)A16,  (float)A32,
                            (float)A64, (float)A128, (float)A256};

    const int lane = threadIdx.x & 63;
    const int wid  = blockIdx.x * WAVES_PER_BLOCK + (threadIdx.x >> 6);
    const size_t row0 = (size_t)wid * ROWS_PER_WAVE;

    const f8 zero8 = {0.f, 0.f, 0.f, 0.f, 0.f, 0.f, 0.f, 0.f};

    // software pipeline: prefetch next row while processing current
    f8 xv = *(const f8*)(x + row0 * T_LEN + lane * 8);

    for (int rr = 0; rr < ROWS_PER_WAVE; ++rr) {
        const size_t base = (row0 + rr) * T_LEN;
        const f8 xc = xv;
        if (rr + 1 < ROWS_PER_WAVE)
            xv = *(const f8*)(x + base + T_LEN + lane * 8);

        // pass 1: lane-local fold from v=0 -> beta of this 8-step segment
        float b = 0.0f;
        #pragma unroll
        for (int j = 0; j < 8; ++j) b = b + (xc[j] - b) * K;

        // inclusive Hillis-Steele scan of affine maps.
        // At step s every participating lane's current segment has length
        // exactly 8*2^s -> uniform multiplier C[s] = A1^(8*2^s).
        #pragma unroll
        for (int s = 0; s < 6; ++s) {
            const float o = __shfl_up(b, 1 << s);
            const float f = fmaf(o, C[s], b);
            b = (lane >= (1 << s)) ? f : b;
        }
        // exclusive prefix = membrane entering this lane's first element
        float u = __shfl_up(b, 1);
        u = (lane == 0) ? 0.0f : u;

        // pass 2: exact serial recurrence within lane; track running max
        float v = u;
        float mx = -1.0f;
        #pragma unroll
        for (int j = 0; j < 8; ++j) {
            v = v + (xc[j] - v) * K;
            mx = fmaxf(mx, v);
        }

        if (__builtin_expect(__ballot(mx >= 0.95f) != 0, 0)) {
            // ~never taken: something within 5% of threshold -> decide with
            // the exact reference recurrence (resets included).
            const float* xr = x + base;
            unsigned m = 0;
            float vv = 0.0f;
            for (int t = 0; t < T_LEN; ++t) {
                const float xt = xr[t];          // wave-uniform broadcast load
                vv = vv + (xt - vv) * K;
                const bool fire = (vv >= 1.0f);
                if (fire) vv = 0.0f;
                if (fire && ((t >> 3) == lane)) m |= (1u << (t & 7));
            }
            f8 s8;
            #pragma unroll
            for (int j = 0; j < 8; ++j)
                s8[j] = ((m >> j) & 1u) ? 1.0f : 0.0f;
            *(f8*)(out + base + lane * 8) = s8;
        } else {
            *(f8*)(out + base + lane * 8) = zero8;
        }
    }
}

extern "C" void kernel_launch(void* const* d_in, const int* in_sizes, int n_in,
                              void* d_out, int out_size, void* d_ws, size_t ws_size,
                              hipStream_t stream) {
    const float* x = (const float*)d_in[0];
    float* out = (float*)d_out;
    const int rows = in_sizes[0] / T_LEN;                 // B*F = 131072
    const int grid = rows / (ROWS_PER_WAVE * WAVES_PER_BLOCK);  // 2048 blocks
    lif_kernel<<<dim3(grid), dim3(64 * WAVES_PER_BLOCK), 0, stream>>>(x, out);
}

// Round 6
// 417.313 us; speedup vs baseline: 1.0826x; 1.0305x over previous
//
#include <hip/hip_runtime.h>

// LIF neuron forward scan, x: [B=64, F=2048, T=512] f32 (scan over contiguous T).
//   v = v + (x_t - v) * (DT/TAU);  s = (v >= 1); v *= (1 - s)
//
// Wave-parallel affine-scan (validated round 5), now with:
//  - DENSE float4 global access: each row = 2x 1KB fully-contiguous wave loads
//    (lane l <- t[4l..4l+4)), redistributed to scan layout (lane owns 8
//    contiguous t) via 16 component-shfls + selects. No 32B-stride patterns.
//  - launch_bounds(256,4): 128-VGPR budget, eliminates any spill risk from
//    round 5's 64-VGPR cap (does not limit achieved occupancy).
//  - Fully decoupled stores: unconditional nontemporal zero-stores issued at
//    the top of each iteration (output is statistically all-zero: threshold
//    is 6.2 sigma; absmax=0.0 confirmed every round). Rare near-threshold
//    rows take an exact serial re-scan behind s_waitcnt vmcnt(0), writing
//    1.0f only at fire positions (r4-validated scheme; rows uniquely owned
//    by one wave -> race-free).
//  - 2-row register pipeline with named buffers (static indexing only).

typedef float f4 __attribute__((ext_vector_type(4)));

#define T_LEN 512
#define ROWS_PER_WAVE 16
#define WAVES_PER_BLOCK 4

__device__ __forceinline__ f4 shfl4(f4 v, int src) {
    f4 r;
    r[0] = __shfl(v[0], src, 64);
    r[1] = __shfl(v[1], src, 64);
    r[2] = __shfl(v[2], src, 64);
    r[3] = __shfl(v[3], src, 64);
    return r;
}

__global__ __launch_bounds__(256, 4)
void lif_kernel(const float* __restrict__ x, float* __restrict__ out) {
    constexpr float  K  = 1.0f / 20.0f;
    constexpr double Kd = (double)(1.0f / 20.0f);
    constexpr double A1 = 1.0 - Kd;
    constexpr double A2 = A1 * A1;
    constexpr double A4 = A2 * A2;
    constexpr double A8 = A4 * A4;           // per-lane segment (8 steps)
    constexpr double A16 = A8 * A8;
    constexpr double A32 = A16 * A16;
    constexpr double A64 = A32 * A32;
    constexpr double A128 = A64 * A64;
    constexpr double A256 = A128 * A128;
    constexpr float C[6] = {(float)A8,  (float)A16,  (float)A32,
                            (float)A64, (float)A128, (float)A256};

    const int lane = threadIdx.x & 63;
    const int wid  = blockIdx.x * WAVES_PER_BLOCK + (threadIdx.x >> 6);
    const size_t row0 = (size_t)wid * ROWS_PER_WAVE;

    // redistribution sources: lane l's scan segment t[8l..8l+8) lives in
    // quads (2l)&63 and (2l+1)&63 of load-A (t<256, lanes<32) / load-B (t>=256).
    const int s0 = (2 * lane) & 63;
    const int s1 = (2 * lane + 1) & 63;
    const bool lo = (lane < 32);

    const f4 zero4 = {0.f, 0.f, 0.f, 0.f};

    // prologue: rows 0 and 1 (A = t[0,256), B = t[256,512); dense f4/lane)
    f4 A0, B0, A1v, B1v;
    {
        const float* p0 = x + row0 * T_LEN + lane * 4;
        A0  = __builtin_nontemporal_load((const f4*)p0);
        B0  = __builtin_nontemporal_load((const f4*)(p0 + 256));
        A1v = __builtin_nontemporal_load((const f4*)(p0 + T_LEN));
        B1v = __builtin_nontemporal_load((const f4*)(p0 + T_LEN + 256));
    }

#define STEP(RR, AV, BV)                                                      \
    {                                                                         \
        const size_t base = (row0 + (RR)) * (size_t)T_LEN;                    \
        float* ob = out + base + lane * 4;                                    \
        /* fire-and-forget zero output: no data dependency at all */          \
        __builtin_nontemporal_store(zero4, (f4*)ob);                          \
        __builtin_nontemporal_store(zero4, (f4*)(ob + 256));                  \
        /* redistribute dense loads -> lane-owns-8-contiguous layout */       \
        const f4 ga = shfl4(AV, s0), gb = shfl4(AV, s1);                      \
        const f4 ha = shfl4(BV, s0), hb = shfl4(BV, s1);                      \
        const f4 q0 = lo ? ga : ha;                                           \
        const f4 q1 = lo ? gb : hb;                                           \
        /* reload this buffer pair for row RR+2 (2-deep pipeline) */          \
        if ((RR) + 2 < ROWS_PER_WAVE) {                                       \
            const float* pr = x + (row0 + (RR) + 2) * T_LEN + lane * 4;       \
            AV = __builtin_nontemporal_load((const f4*)pr);                   \
            BV = __builtin_nontemporal_load((const f4*)(pr + 256));           \
        }                                                                     \
        /* pass 1: lane-local fold from v=0 -> segment beta */                \
        float b = 0.0f;                                                       \
        _Pragma("unroll")                                                     \
        for (int j = 0; j < 4; ++j) b = b + (q0[j] - b) * K;                  \
        _Pragma("unroll")                                                     \
        for (int j = 0; j < 4; ++j) b = b + (q1[j] - b) * K;                  \
        /* 6-step Hillis-Steele scan of affine maps (uniform C[s]) */         \
        _Pragma("unroll")                                                     \
        for (int s = 0; s < 6; ++s) {                                         \
            const float o = __shfl_up(b, 1 << s);                             \
            const float f = fmaf(o, C[s], b);                                 \
            b = (lane >= (1 << s)) ? f : b;                                   \
        }                                                                     \
        float u = __shfl_up(b, 1);                                            \
        u = (lane == 0) ? 0.0f : u;                                           \
        /* pass 2: exact serial recurrence in-lane; track max */              \
        float v = u;                                                          \
        float mx = -1.0f;                                                     \
        _Pragma("unroll")                                                     \
        for (int j = 0; j < 4; ++j) {                                         \
            v = v + (q0[j] - v) * K;                                          \
            mx = fmaxf(mx, v);                                                \
        }                                                                     \
        _Pragma("unroll")                                                     \
        for (int j = 0; j < 4; ++j) {                                         \
            v = v + (q1[j] - v) * K;                                          \
            mx = fmaxf(mx, v);                                                \
        }                                                                     \
        if (__builtin_expect(__ballot(mx >= 0.95f) != 0, 0)) {                \
            /* ~never: near-threshold row -> exact reference re-scan. */      \
            asm volatile("s_waitcnt vmcnt(0)" ::: "memory");                  \
            const float* xr = x + base;                                       \
            unsigned m = 0;                                                   \
            float vv = 0.0f;                                                  \
            for (int t = 0; t < T_LEN; ++t) {                                 \
                const float xt = xr[t];                                       \
                vv = vv + (xt - vv) * K;                                      \
                const bool fire = (vv >= 1.0f);                               \
                if (fire) vv = 0.0f;                                          \
                if (fire && ((t >> 3) == lane)) m |= (1u << (t & 7));         \
            }                                                                 \
            float* orow = out + base + (size_t)lane * 8;                      \
            while (m) {                                                       \
                const int j = __builtin_ctz(m);                               \
                m &= m - 1;                                                   \
                orow[j] = 1.0f;                                               \
            }                                                                 \
        }                                                                     \
    }

    STEP(0,  A0, B0)  STEP(1,  A1v, B1v)
    STEP(2,  A0, B0)  STEP(3,  A1v, B1v)
    STEP(4,  A0, B0)  STEP(5,  A1v, B1v)
    STEP(6,  A0, B0)  STEP(7,  A1v, B1v)
    STEP(8,  A0, B0)  STEP(9,  A1v, B1v)
    STEP(10, A0, B0)  STEP(11, A1v, B1v)
    STEP(12, A0, B0)  STEP(13, A1v, B1v)
    STEP(14, A0, B0)  STEP(15, A1v, B1v)
#undef STEP
}

extern "C" void kernel_launch(void* const* d_in, const int* in_sizes, int n_in,
                              void* d_out, int out_size, void* d_ws, size_t ws_size,
                              hipStream_t stream) {
    const float* x = (const float*)d_in[0];
    float* out = (float*)d_out;
    const int rows = in_sizes[0] / T_LEN;                       // B*F = 131072
    const int grid = rows / (ROWS_PER_WAVE * WAVES_PER_BLOCK);  // 2048 blocks
    lif_kernel<<<dim3(grid), dim3(64 * WAVES_PER_BLOCK), 0, stream>>>(x, out);
}